// Round 1
// baseline (658.175 us; speedup 1.0000x reference)
//
#include <hip/hip_runtime.h>
#include <float.h>

#define N 4096
#define FI 44
#define RK 11
#define KNN 16
#define NSEL 25   // K + 9 ranks kept
#define NROW 4    // rows per block in dist/topk
#define NPB 4     // nodes per block in edge kernel
#define EPB 64    // edges per block (NPB * KNN)

// ---------------- K1: squared row norms ----------------
__global__ void k_sqnorm(const float* __restrict__ h, float* __restrict__ sq) {
  int i = blockIdx.x * blockDim.x + threadIdx.x;
  if (i < N) {
    const float4* hr = reinterpret_cast<const float4*>(h + (size_t)i * FI);
    float s = 0.f;
#pragma unroll
    for (int c = 0; c < FI / 4; c++) { float4 v = hr[c]; s += v.x*v.x + v.y*v.y + v.z*v.z + v.w*v.w; }
    sq[i] = s;
  }
}

// ---------------- K2: distance rows + top-25 selection ----------------
// block = NROW rows; 256 threads compute D rows into LDS; then wave w selects
// row w's 25 smallest (tie-break: smaller index, matching jax.lax.top_k).
__global__ __launch_bounds__(256) void k_dist_topk(const float* __restrict__ h,
                                                   const float* __restrict__ sq,
                                                   const float* __restrict__ mask,
                                                   int* __restrict__ ctr_idx,
                                                   int* __restrict__ nbr_idx) {
  __shared__ __align__(16) float drow[NROW][N];
  __shared__ __align__(16) float hi[NROW][FI];
  __shared__ float sqi[NROW];
  const int tid = threadIdx.x;
  const int r0 = blockIdx.x * NROW;

  for (int t = tid; t < NROW * FI; t += 256) hi[t / FI][t % FI] = h[(size_t)(r0 + t / FI) * FI + (t % FI)];
  if (tid < NROW) sqi[tid] = sq[r0 + tid];
  __syncthreads();

  for (int s = 0; s < N / 256; s++) {
    int j = s * 256 + tid;
    const float4* hj = reinterpret_cast<const float4*>(h + (size_t)j * FI);
    float4 a[FI / 4];
#pragma unroll
    for (int c = 0; c < FI / 4; c++) a[c] = hj[c];
    float sqj = sq[j];
#pragma unroll
    for (int rr = 0; rr < NROW; rr++) {
      const float4* hir = reinterpret_cast<const float4*>(&hi[rr][0]);
      float dot = 0.f;
#pragma unroll
      for (int c = 0; c < FI / 4; c++) {
        float4 b = hir[c];
        dot += a[c].x*b.x + a[c].y*b.y + a[c].z*b.z + a[c].w*b.w;
      }
      int row = r0 + rr;
      // D = |sq_i + sq_j - 2 dot| * mask - 2*eye  (exact reference order)
      float D = fabsf(sqi[rr] + sqj - 2.f * dot) * mask[(size_t)row * N + j];
      if (j == row) D -= 2.f;
      drow[rr][j] = D;
    }
  }
  __syncthreads();

  // wave w handles row w: lane keeps argmin over its 64 strided elements;
  // after each extraction only the winning lane rescans.
  const int w = tid >> 6, lane = tid & 63;
  float* dr = drow[w];
  float bv = FLT_MAX; int bi = N;
  for (int m = 0; m < N / 64; m++) {
    int j = m * 64 + lane;
    float v = dr[j];
    if (v < bv) { bv = v; bi = j; }   // strict < keeps smaller j on ties
  }
  for (int it = 0; it < NSEL; it++) {
    float rv = bv; int ri = bi;
#pragma unroll
    for (int off = 1; off < 64; off <<= 1) {
      float ov = __shfl_xor(rv, off, 64);
      int   oi = __shfl_xor(ri, off, 64);
      if (ov < rv || (ov == rv && oi < ri)) { rv = ov; ri = oi; }
    }
    if (lane == 0) {
      int row = r0 + w;
      if (it == 0) ctr_idx[row] = ri;                       // rank 0 = center (self)
      else if (it >= 9) nbr_idx[row * KNN + (it - 9)] = ri; // ranks 9..24
    }
    if ((ri & 63) == lane) {   // owner lane removes winner and rescans
      dr[ri] = FLT_MAX;
      bv = FLT_MAX; bi = N;
      for (int m = 0; m < N / 64; m++) {
        int j = m * 64 + lane;
        float v = dr[j];
        if (v < bv) { bv = v; bi = j; }
      }
    }
  }
}

// ---------------- K3: fused edge-conditioned conv ----------------
// block = 4 nodes (64 edges), 256 threads = 32 edge-pairs x 8 f-slices.
// LDS weight buffer (85 KB) phased: W_labT -> W_th1T -> W_th2T.
__global__ __launch_bounds__(256) void k_edge(
    const float* __restrict__ h,
    const int* __restrict__ ctr_idx, const int* __restrict__ nbr_idx,
    const float* __restrict__ W_lab, const float* __restrict__ b_lab,
    const float* __restrict__ W1, const float* __restrict__ b1,
    const float* __restrict__ W2, const float* __restrict__ b2,
    const float* __restrict__ Wl, const float* __restrict__ bl,
    float* __restrict__ out)
{
  __shared__ __align__(16) float WT[484 * FI];   // transposed weights: WT[n*44+c] = W[c*Nn+n]
  __shared__ __align__(16) float x1s[EPB][FI];   // neighbor features
  __shared__ __align__(16) float lbs[EPB][FI];   // labels, then lab
  __shared__ __align__(16) float hcs[NPB][FI];   // center features
  __shared__ float dls[EPB];                     // ||labels||^2
  __shared__ float tfs[EPB][RK];                 // t (then t * thetal)
  __shared__ float oacc[NPB][FI];                // output accumulator

  const int tid = threadIdx.x;
  const int b = blockIdx.x;

  for (int t = tid; t < NPB * FI; t += 256) oacc[t / FI][t % FI] = 0.f;
  for (int t = tid; t < NPB * FI; t += 256) {
    int nn = t / FI, c = t % FI;
    hcs[nn][c] = h[(size_t)ctr_idx[b * NPB + nn] * FI + c];
  }
  for (int t = tid; t < EPB * FI; t += 256) {
    int e = t / FI, c = t % FI;
    int nb = nbr_idx[(b * NPB + (e >> 4)) * KNN + (e & 15)];
    x1s[e][c] = h[(size_t)nb * FI + c];
  }
  __syncthreads();
  for (int t = tid; t < EPB * FI; t += 256) {
    int e = t / FI, c = t % FI;
    lbs[e][c] = x1s[e][c] - hcs[e >> 4][c];
  }
  __syncthreads();
  if (tid < EPB) {
    const float4* L = reinterpret_cast<const float4*>(&lbs[tid][0]);
    float s = 0.f;
#pragma unroll
    for (int c = 0; c < FI / 4; c++) { float4 v = L[c]; s += v.x*v.x + v.y*v.y + v.z*v.z + v.w*v.w; }
    dls[tid] = s;
  }
  // stage W_labT (coalesced global read, transposed LDS write)
  for (int t = tid; t < FI * FI; t += 256) {
    int c = t / FI, f = t % FI;
    WT[f * FI + c] = W_lab[t];
  }
  __syncthreads();

  const int q = tid & 7, pp = tid >> 3;
  const int e0 = pp, e1 = pp + 32;

  // ---- P1: lab = leaky_relu(labels @ W_lab + b_lab) for f-slice of both edges
  float la0[6], la1[6];
  {
    const float4* A = reinterpret_cast<const float4*>(&lbs[e0][0]);
    const float4* B = reinterpret_cast<const float4*>(&lbs[e1][0]);
#pragma unroll
    for (int m = 0; m < 6; m++) {
      int f = q + 8 * m;
      if (f < FI) {
        float th0 = b_lab[f], th1 = th0;
        const float4* Wn = reinterpret_cast<const float4*>(&WT[f * FI]);
#pragma unroll
        for (int cc = 0; cc < FI / 4; cc++) {
          float4 wv = Wn[cc]; float4 av = A[cc]; float4 bv = B[cc];
          th0 += wv.x*av.x + wv.y*av.y + wv.z*av.z + wv.w*av.w;
          th1 += wv.x*bv.x + wv.y*bv.y + wv.z*bv.z + wv.w*bv.w;
        }
        la0[m] = th0 >= 0.f ? th0 : 0.2f * th0;
        la1[m] = th1 >= 0.f ? th1 : 0.2f * th1;
      }
    }
  }
  __syncthreads();
#pragma unroll
  for (int m = 0; m < 6; m++) {
    int f = q + 8 * m;
    if (f < FI) { lbs[e0][f] = la0[m]; lbs[e1][f] = la1[m]; }
  }
  for (int t = tid; t < 484 * FI; t += 256) {   // stage W1T
    int c = t / 484, n = t % 484;
    WT[n * FI + c] = W1[t];
  }
  __syncthreads();

  // cache lab (both edges) in registers; x1 f-slices
  float lab0[FI], lab1[FI];
  {
    const float4* A = reinterpret_cast<const float4*>(&lbs[e0][0]);
    const float4* B = reinterpret_cast<const float4*>(&lbs[e1][0]);
#pragma unroll
    for (int c = 0; c < FI / 4; c++) {
      float4 av = A[c], bv = B[c];
      lab0[4*c] = av.x; lab0[4*c+1] = av.y; lab0[4*c+2] = av.z; lab0[4*c+3] = av.w;
      lab1[4*c] = bv.x; lab1[4*c+1] = bv.y; lab1[4*c+2] = bv.z; lab1[4*c+3] = bv.w;
    }
  }
  float xa[6], xb[6];
#pragma unroll
  for (int m = 0; m < 6; m++) { int f = q + 8 * m; if (f < FI) { xa[m] = x1s[e0][f]; xb[m] = x1s[e1][f]; } }

  // ---- P2: t[e][r] = sum_f (b1 + lab@W1)[r,f] * x1[e,f]  (shuffle-reduce over q)
  for (int r = 0; r < RK; r++) {
    float tp0 = 0.f, tp1 = 0.f;
#pragma unroll
    for (int m = 0; m < 6; m++) {
      int f = q + 8 * m;
      if (f < FI) {
        int n = r * FI + f;
        float th0 = b1[n], th1 = th0;
        const float4* Wn = reinterpret_cast<const float4*>(&WT[n * FI]);
#pragma unroll
        for (int cc = 0; cc < FI / 4; cc++) {
          float4 wv = Wn[cc];
          th0 += wv.x*lab0[4*cc] + wv.y*lab0[4*cc+1] + wv.z*lab0[4*cc+2] + wv.w*lab0[4*cc+3];
          th1 += wv.x*lab1[4*cc] + wv.y*lab1[4*cc+1] + wv.z*lab1[4*cc+2] + wv.w*lab1[4*cc+3];
        }
        tp0 += th0 * xa[m];
        tp1 += th1 * xb[m];
      }
    }
#pragma unroll
    for (int off = 1; off < 8; off <<= 1) {
      tp0 += __shfl_xor(tp0, off, 64);
      tp1 += __shfl_xor(tp1, off, 64);
    }
    if (q == 0) { tfs[e0][r] = tp0; tfs[e1][r] = tp1; }
  }
  __syncthreads();

  // ---- P3: t *= (lab @ W_thl + b_thl); stage W2T concurrently
  for (int task = tid; task < EPB * RK; task += 256) {
    int e = task / RK, r = task - (task / RK) * RK;
    float tl = bl[r];
    const float* le = &lbs[e][0];
#pragma unroll
    for (int c = 0; c < FI; c++) tl += le[c] * Wl[c * RK + r];
    tfs[e][r] *= tl;
  }
  for (int t = tid; t < 484 * FI; t += 256) {   // stage W2T
    int c = t / 484, n = t % 484;
    WT[n * FI + c] = W2[t];
  }
  __syncthreads();

  // ---- P4: x[e][f] = sum_r (b2 + lab@W2)[r,f] * t[e][r]; weighted mean into oacc
  float xo0[6] = {0,0,0,0,0,0}, xo1[6] = {0,0,0,0,0,0};
  for (int r = 0; r < RK; r++) {
    float t0 = tfs[e0][r], t1 = tfs[e1][r];
#pragma unroll
    for (int m = 0; m < 6; m++) {
      int f = q + 8 * m;
      if (f < FI) {
        int n = r * FI + f;
        float th0 = b2[n], th1 = th0;
        const float4* Wn = reinterpret_cast<const float4*>(&WT[n * FI]);
#pragma unroll
        for (int cc = 0; cc < FI / 4; cc++) {
          float4 wv = Wn[cc];
          th0 += wv.x*lab0[4*cc] + wv.y*lab0[4*cc+1] + wv.z*lab0[4*cc+2] + wv.w*lab0[4*cc+3];
          th1 += wv.x*lab1[4*cc] + wv.y*lab1[4*cc+1] + wv.z*lab1[4*cc+2] + wv.w*lab1[4*cc+3];
        }
        xo0[m] += th0 * t0;
        xo1[m] += th1 * t1;
      }
    }
  }
  float w0 = expf(-dls[e0] / 10.0f) * (1.0f / 16.0f);
  float w1 = expf(-dls[e1] / 10.0f) * (1.0f / 16.0f);
  int nd0 = e0 >> 4, nd1 = e1 >> 4;
#pragma unroll
  for (int m = 0; m < 6; m++) {
    int f = q + 8 * m;
    if (f < FI) {
      atomicAdd(&oacc[nd0][f], xo0[m] * w0);
      atomicAdd(&oacc[nd1][f], xo1[m] * w1);
    }
  }
  __syncthreads();
  for (int t = tid; t < NPB * FI; t += 256) {
    int nn = t / FI, c = t % FI;
    out[(size_t)(b * NPB + nn) * FI + c] = oacc[nn][c];
  }
}

extern "C" void kernel_launch(void* const* d_in, const int* in_sizes, int n_in,
                              void* d_out, int out_size, void* d_ws, size_t ws_size,
                              hipStream_t stream) {
  const float* h     = (const float*)d_in[0];
  const float* mask  = (const float*)d_in[1];
  const float* W_lab = (const float*)d_in[2];
  const float* b_lab = (const float*)d_in[3];
  const float* W1    = (const float*)d_in[4];
  const float* b1    = (const float*)d_in[5];
  const float* W2    = (const float*)d_in[6];
  const float* b2    = (const float*)d_in[7];
  const float* Wl    = (const float*)d_in[8];
  const float* bl    = (const float*)d_in[9];

  float* sq = (float*)d_ws;
  int* ctr  = (int*)(sq + N);
  int* nbr  = ctr + N;

  k_sqnorm<<<N / 256, 256, 0, stream>>>(h, sq);
  k_dist_topk<<<N / NROW, 256, 0, stream>>>(h, sq, mask, ctr, nbr);
  k_edge<<<N / NPB, 256, 0, stream>>>(h, ctr, nbr, W_lab, b_lab, W1, b1, W2, b2, Wl, bl, (float*)d_out);
}